// Round 13
// baseline (400.861 us; speedup 1.0000x reference)
//
#include <hip/hip_runtime.h>
#include <hip/hip_bf16.h>
#include <math.h>

#define N_NODES 10000
#define N_EDGES 640000
#define C 128
#define BF 16
#define EPB 32   // edges per msg block

typedef float vfloat2 __attribute__((ext_vector_type(2)));

__device__ __forceinline__ float2 bf2_to_f2(unsigned u) {
    union { unsigned x; float f; } lo, hi;
    lo.x = (u & 0xffffu) << 16;
    hi.x = u & 0xffff0000u;
    float2 r; r.x = lo.f; r.y = hi.f; return r;
}

// tanh-approx GELU, exp2 domain; |err vs exact| <= ~4e-4, branchless.
__device__ __forceinline__ float fast_gelu(float z) {
    float z2 = z * z;
    float p  = z * fmaf(0.044715f, z2, 1.0f);
    float e  = __builtin_amdgcn_exp2f(-2.3022082f * p);
    float r  = __builtin_amdgcn_rcpf(1.0f + e);
    return z * r;
}

__device__ __forceinline__ float2 fma2(float a, float2 b, float2 c) {
    float2 r; r.x = fmaf(a, b.x, c.x); r.y = fmaf(a, b.y, c.y); return r;
}

__device__ __forceinline__ unsigned pack_bf16x2(float a, float b) {
    __hip_bfloat16 h0 = __float2bfloat16(a);
    __hip_bfloat16 h1 = __float2bfloat16(b);
    unsigned short u0, u1;
    __builtin_memcpy(&u0, &h0, 2);
    __builtin_memcpy(&u1, &h1, 2);
    return (unsigned)u0 | ((unsigned)u1 << 16);
}

// --- K1: fused x->bf16 convert (blocks 0..1249) + degree atomics (rest) ---
__global__ __launch_bounds__(256) void k_pre(
    const float* __restrict__ x, __hip_bfloat16* __restrict__ xb,
    const int* __restrict__ ei, int* __restrict__ dr, int* __restrict__ dc)
{
    int b = blockIdx.x;
    if (b < 1250) {
        int i = (b * 256 + threadIdx.x) * 4;
        float4 v = *(const float4*)(x + i);
        xb[i + 0] = __float2bfloat16(v.x);
        xb[i + 1] = __float2bfloat16(v.y);
        xb[i + 2] = __float2bfloat16(v.z);
        xb[i + 3] = __float2bfloat16(v.w);
    } else {
        int e = (b - 1250) * 256 + threadIdx.x;   // 2500 blocks cover N_EDGES
        atomicAdd(&dr[ei[e]], 1);
        atomicAdd(&dc[ei[N_EDGES + e]], 1);
    }
}

// --- K2: exclusive scan of dc -> off, plus inv-sqrt degrees ---
__global__ __launch_bounds__(1024) void k_scan(
    const int* __restrict__ dr, const int* __restrict__ dc,
    int* __restrict__ off, float* __restrict__ ir, float* __restrict__ ic)
{
    __shared__ int shp[1024];
    int t = threadIdx.x;
    int base = t * 10;
    int loc[10];
    int s = 0;
#pragma unroll
    for (int j = 0; j < 10; j++) {
        int i = base + j;
        int v = (i < N_NODES) ? dc[i] : 0;
        loc[j] = s;
        s += v;
    }
    shp[t] = s;
    __syncthreads();
    for (int st = 1; st < 1024; st <<= 1) {
        int a = (t >= st) ? shp[t - st] : 0;
        __syncthreads();
        shp[t] += a;
        __syncthreads();
    }
    int excl = shp[t] - s;
#pragma unroll
    for (int j = 0; j < 10; j++) {
        int i = base + j;
        if (i < N_NODES) {
            off[i] = excl + loc[j];
            ir[i] = rsqrtf((float)(dr[i] + 1));
            ic[i] = rsqrtf((float)(dc[i] + 1));
        }
    }
    if (t == 1023) off[N_NODES] = shp[1023];
}

// --- K3 (fused): blocks [0,20000): edge-order UNSCALED messages, sequential
//     NT writes. blocks [20000,22500): bucket scatter + prefolded scale. ---
__global__ __launch_bounds__(256) void k_msgscatter(
    const int* __restrict__ ei, const float* __restrict__ ew,
    const float* __restrict__ ea,
    const __hip_bfloat16* __restrict__ xb,
    const float* __restrict__ Wb, const float* __restrict__ bb,
    const int* __restrict__ off, int* __restrict__ cur,
    const float* __restrict__ ir, const float* __restrict__ ic,
    __hip_bfloat16* __restrict__ msg,
    int* __restrict__ bucket, float* __restrict__ ss)
{
    int b = blockIdx.x;
    int t = threadIdx.x;

    if (b >= N_EDGES / EPB) {                     // ---- scatter part ----
        int e = (b - N_EDGES / EPB) * 256 + t;    // 2500 blocks cover N_EDGES
        int r = ei[e];
        int c = ei[N_EDGES + e];
        int pos = atomicAdd(&cur[c], 1);
        int slot = off[c] + pos;
        bucket[slot] = e;
        ss[slot] = ir[r] * ic[c] * ew[e];
        return;
    }

    // ---- msg part: 32 edges, 4 waves x 64 channel-pairs ----
    int e0 = b * EPB;
    int p = t & 63;                               // channel pair
    int w = t >> 6;                               // wave 0..3

    __shared__ __align__(16) float sl_ea[EPB][BF];
    __shared__ int sl_r[EPB];
    {
        vfloat2 v = __builtin_nontemporal_load(
            (const vfloat2*)(ea + (size_t)e0 * BF) + t);
        ((vfloat2*)&sl_ea[0][0])[t] = v;
    }
    if (t < EPB) sl_r[t] = ei[e0 + t];

    int c0 = p * 2;
    float2 wbv[BF];
#pragma unroll
    for (int k = 0; k < BF; k++) wbv[k] = *(const float2*)(Wb + (size_t)k * C + c0);
    float2 bbv = *(const float2*)(bb + c0);
    __syncthreads();

#pragma unroll 4
    for (int jj = 0; jj < EPB / 4; jj++) {
        int j = w + jj * 4;                       // this wave's edge
        const float4* er = (const float4*)sl_ea[j];
        float4 q0 = er[0], q1 = er[1], q2 = er[2], q3 = er[3];

        float2 emb = bbv;
        emb = fma2(q0.x, wbv[0],  emb); emb = fma2(q0.y, wbv[1],  emb);
        emb = fma2(q0.z, wbv[2],  emb); emb = fma2(q0.w, wbv[3],  emb);
        emb = fma2(q1.x, wbv[4],  emb); emb = fma2(q1.y, wbv[5],  emb);
        emb = fma2(q1.z, wbv[6],  emb); emb = fma2(q1.w, wbv[7],  emb);
        emb = fma2(q2.x, wbv[8],  emb); emb = fma2(q2.y, wbv[9],  emb);
        emb = fma2(q2.z, wbv[10], emb); emb = fma2(q2.w, wbv[11], emb);
        emb = fma2(q3.x, wbv[12], emb); emb = fma2(q3.y, wbv[13], emb);
        emb = fma2(q3.z, wbv[14], emb); emb = fma2(q3.w, wbv[15], emb);

        int r = sl_r[j];
        float2 xf = bf2_to_f2(*((const unsigned*)(xb + (size_t)r * C) + p));
        float m0 = fast_gelu(xf.x + emb.x);
        float m1 = fast_gelu(xf.y + emb.y);
        __builtin_nontemporal_store(pack_bf16x2(m0, m1),
            (unsigned*)(msg + (size_t)(e0 + j) * C) + p);   // sequential rows
    }
}

// --- K4: one block per node, 4 waves; wave reads whole msg rows (64x4 B),
//     scales by ss, fp32-accumulates; self-loop + split GEMV epilogue. ---
__global__ __launch_bounds__(256) void k_sum(
    const __hip_bfloat16* __restrict__ msg,
    const int* __restrict__ bucket, const float* __restrict__ ss,
    const __hip_bfloat16* __restrict__ xb,
    const float* __restrict__ ir, const float* __restrict__ ic,
    const int* __restrict__ off,
    const float* __restrict__ Wl, const float* __restrict__ bl,
    float* __restrict__ out)
{
    int n = blockIdx.x;
    int t = threadIdx.x;
    int w = t >> 6;
    int lane = t & 63;
    int c0 = lane * 2;

    int i0 = off[n], i1 = off[n + 1];

    float2 a = make_float2(0.f, 0.f);
    int i = i0 + w;                       // wave w: slots i0+w, i0+w+4, ...
    if (i < i1) {
        int   eN = bucket[i];             // wave-uniform -> broadcast
        float sN = ss[i];
        unsigned uN = *((const unsigned*)(msg + (size_t)eN * C) + lane);
        for (;;) {
            int inext = i + 4;
            bool more = inext < i1;
            int e2 = 0; float s2 = 0.f; unsigned u2 = 0;
            if (more) {                   // 1-ahead prefetch
                e2 = bucket[inext];
                s2 = ss[inext];
                u2 = *((const unsigned*)(msg + (size_t)e2 * C) + lane);
            }
            float2 f = bf2_to_f2(uN);
            a.x = fmaf(f.x, sN, a.x);
            a.y = fmaf(f.y, sN, a.y);
            if (!more) break;
            i = inext; sN = s2; uN = u2;
        }
    }

    __shared__ float shp[4][C];
    __shared__ float shs[C];
    __shared__ float sho[2][C];
    shp[w][c0] = a.x; shp[w][c0 + 1] = a.y;
    __syncthreads();
    if (t < C) {
        float v = shp[0][t] + shp[1][t] + shp[2][t] + shp[3][t];
        float sl = ir[n] * ic[n];
        float xv = __bfloat162float(xb[(size_t)n * C + t]);
        shs[t] = v + fast_gelu(xv) * sl;
    }
    __syncthreads();

    int ch = t & 127, half = t >> 7;
    float o = 0.f;
    const float4* shv = (const float4*)shs + half * 16;
    const float* wcol = Wl + (size_t)(half * 64) * C + ch;
#pragma unroll 8
    for (int k4 = 0; k4 < 16; k4++) {
        float4 sv = shv[k4];
        o = fmaf(sv.x, wcol[(size_t)(k4 * 4 + 0) * C], o);
        o = fmaf(sv.y, wcol[(size_t)(k4 * 4 + 1) * C], o);
        o = fmaf(sv.z, wcol[(size_t)(k4 * 4 + 2) * C], o);
        o = fmaf(sv.w, wcol[(size_t)(k4 * 4 + 3) * C], o);
    }
    sho[half][ch] = o;
    __syncthreads();
    if (t < C) out[(size_t)n * C + t] = bl[t] + sho[0][t] + sho[1][t];
}

// ---------------- fallback path (round-5 structure, ws-lean, proven) --------
__global__ void k_scatter_fb(const int* __restrict__ ei, const int* __restrict__ off,
                             int* __restrict__ cur, int* __restrict__ bucket) {
    int e = blockIdx.x * blockDim.x + threadIdx.x;
    if (e < N_EDGES) {
        int c = ei[N_EDGES + e];
        int pos = atomicAdd(&cur[c], 1);
        bucket[off[c] + pos] = e;
    }
}

template <bool USEBF>
__global__ __launch_bounds__(512) void k_node_fb(
    const float* __restrict__ x, const __hip_bfloat16* __restrict__ xb,
    const float* __restrict__ ea, const float* __restrict__ ew,
    const float* __restrict__ Wb, const float* __restrict__ bb,
    const int* __restrict__ ei,
    const float* __restrict__ ir, const float* __restrict__ ic,
    const int* __restrict__ off, const int* __restrict__ bucket,
    const float* __restrict__ Wl, const float* __restrict__ bl,
    float* __restrict__ out)
{
    int n = blockIdx.x;
    int t = threadIdx.x & (C - 1);
    int g = threadIdx.x >> 7;
    float icn = ic[n];
    float wb[BF];
#pragma unroll
    for (int k = 0; k < BF; k++) wb[k] = Wb[(size_t)k * C + t];
    float bbt = bb[t];
    float acc = 0.0f;
    if (g == 0) {
        float xv = USEBF ? __bfloat162float(xb[(size_t)n * C + t]) : x[(size_t)n * C + t];
        acc = fast_gelu(xv) * (ir[n] * icn);
    }
    int o0 = off[n], o1 = off[n + 1];
    for (int i = o0 + g; i < o1; i += 4) {
        int e = __builtin_amdgcn_readfirstlane(bucket[i]);
        int r = ei[e];
        float s = ir[r] * icn * ew[e];
        const float4* eapt = (const float4*)(ea + (size_t)e * BF);
        float4 q0 = eapt[0], q1 = eapt[1], q2 = eapt[2], q3 = eapt[3];
        float emb = bbt;
        emb = fmaf(q0.x, wb[0], emb);  emb = fmaf(q0.y, wb[1], emb);
        emb = fmaf(q0.z, wb[2], emb);  emb = fmaf(q0.w, wb[3], emb);
        emb = fmaf(q1.x, wb[4], emb);  emb = fmaf(q1.y, wb[5], emb);
        emb = fmaf(q1.z, wb[6], emb);  emb = fmaf(q1.w, wb[7], emb);
        emb = fmaf(q2.x, wb[8], emb);  emb = fmaf(q2.y, wb[9], emb);
        emb = fmaf(q2.z, wb[10], emb); emb = fmaf(q2.w, wb[11], emb);
        emb = fmaf(q3.x, wb[12], emb); emb = fmaf(q3.y, wb[13], emb);
        emb = fmaf(q3.z, wb[14], emb); emb = fmaf(q3.w, wb[15], emb);
        float xv = USEBF ? __bfloat162float(xb[(size_t)r * C + t]) : x[(size_t)r * C + t];
        acc = fmaf(fast_gelu(xv + emb), s, acc);
    }
    __shared__ float shp[4][C];
    __shared__ float shs[C];
    shp[g][t] = acc;
    __syncthreads();
    if (threadIdx.x < C) {
        int k = threadIdx.x;
        shs[k] = shp[0][k] + shp[1][k] + shp[2][k] + shp[3][k];
    }
    __syncthreads();
    float o = 0.0f;
    int k0 = g * 32;
#pragma unroll 8
    for (int j = 0; j < 32; j++) {
        int k = k0 + j;
        o = fmaf(shs[k], Wl[(size_t)k * C + t], o);
    }
    shp[g][t] = o;
    __syncthreads();
    if (threadIdx.x < C) {
        int c = threadIdx.x;
        out[(size_t)n * C + c] = bl[c] + shp[0][c] + shp[1][c] + shp[2][c] + shp[3][c];
    }
}

__global__ __launch_bounds__(256) void k_cvt_fb(const float* __restrict__ x,
                                                __hip_bfloat16* __restrict__ xb) {
    int i = (blockIdx.x * 256 + threadIdx.x) * 4;
    float4 v = *(const float4*)(x + i);
    xb[i + 0] = __float2bfloat16(v.x);
    xb[i + 1] = __float2bfloat16(v.y);
    xb[i + 2] = __float2bfloat16(v.z);
    xb[i + 3] = __float2bfloat16(v.w);
}

__global__ void k_deg_fb(const int* __restrict__ ei, int* __restrict__ dr, int* __restrict__ dc) {
    int e = blockIdx.x * blockDim.x + threadIdx.x;
    if (e < N_EDGES) {
        atomicAdd(&dr[ei[e]], 1);
        atomicAdd(&dc[ei[N_EDGES + e]], 1);
    }
}

extern "C" void kernel_launch(void* const* d_in, const int* in_sizes, int n_in,
                              void* d_out, int out_size, void* d_ws, size_t ws_size,
                              hipStream_t stream) {
    const float* x  = (const float*)d_in[0];
    const float* ea = (const float*)d_in[1];
    const float* ew = (const float*)d_in[2];
    const float* Wb = (const float*)d_in[3];
    const float* bb = (const float*)d_in[4];
    const float* Wl = (const float*)d_in[5];
    const float* bl = (const float*)d_in[6];
    const int*   ei = (const int*)d_in[7];
    float* out = (float*)d_out;

    // full layout (u32 units): msg 40,960,000 | xb 640,000 | bucket 640,000 |
    //   ss 640,000 | off 10,304 | dr/dc/cur 3x10,240 | ir/ic 2x10,240
    const size_t msg_elems = (size_t)N_EDGES * C;    // 81,920,000 bf16
    const size_t need_full = (size_t)(40960000 + 3 * 640000 + 10304 + 5 * 10240) * 4;
    const size_t need_bf   = (size_t)(640000 + 640000 + 10304 + 5 * 10240) * 4;

    unsigned* w32 = (unsigned*)d_ws;
    if (ws_size >= need_full) {
        __hip_bfloat16* msg = (__hip_bfloat16*)w32;
        __hip_bfloat16* xb  = (__hip_bfloat16*)(w32 + 40960000);
        int*   bucket = (int*)(w32 + 40960000 + 640000);
        float* ss     = (float*)(bucket + 640000);
        int*   off    = (int*)(ss + 640000);
        int*   dr     = off + 10304;
        int*   dc     = dr + 10240;
        int*   cur    = dc + 10240;
        float* ir     = (float*)(cur + 10240);
        float* ic     = ir + 10240;

        hipMemsetAsync(dr, 0, 3 * 10240 * sizeof(int), stream);   // dr, dc, cur
        k_pre<<<3750, 256, 0, stream>>>(x, xb, ei, dr, dc);
        k_scan<<<1, 1024, 0, stream>>>(dr, dc, off, ir, ic);
        k_msgscatter<<<N_EDGES / EPB + 2500, 256, 0, stream>>>(
            ei, ew, ea, xb, Wb, bb, off, cur, ir, ic, msg, bucket, ss);
        k_sum<<<N_NODES, 256, 0, stream>>>(msg, bucket, ss, xb, ir, ic, off, Wl, bl, out);
    } else {
        bool usebf = ws_size >= need_bf;
        __hip_bfloat16* xb = (__hip_bfloat16*)w32;
        int* bucket = (int*)(w32 + (usebf ? 640000 : 0));
        int* off    = bucket + 640000;
        int* dr     = off + 10304;
        int* dc     = dr + 10240;
        int* cur    = dc + 10240;
        float* ir   = (float*)(cur + 10240);
        float* ic   = ir + 10240;

        hipMemsetAsync(dr, 0, 3 * 10240 * sizeof(int), stream);
        if (usebf) k_cvt_fb<<<1250, 256, 0, stream>>>(x, xb);
        k_deg_fb<<<(N_EDGES + 255) / 256, 256, 0, stream>>>(ei, dr, dc);
        k_scan<<<1, 1024, 0, stream>>>(dr, dc, off, ir, ic);
        k_scatter_fb<<<(N_EDGES + 255) / 256, 256, 0, stream>>>(ei, off, cur, bucket);
        if (usebf)
            k_node_fb<true><<<N_NODES, 512, 0, stream>>>(x, xb, ea, ew, Wb, bb, ei, ir, ic, off, bucket, Wl, bl, out);
        else
            k_node_fb<false><<<N_NODES, 512, 0, stream>>>(x, xb, ea, ew, Wb, bb, ei, ir, ic, off, bucket, Wl, bl, out);
    }
}

// Round 14
// 359.318 us; speedup vs baseline: 1.1156x; 1.1156x over previous
//
#include <hip/hip_runtime.h>
#include <hip/hip_bf16.h>
#include <math.h>

#define N_NODES 10000
#define N_EDGES 640000
#define C 128
#define BF 16
#define SPB 32   // slots per k_msg2 block

__device__ __forceinline__ float2 bf2_to_f2(unsigned u) {
    union { unsigned x; float f; } lo, hi;
    lo.x = (u & 0xffffu) << 16;
    hi.x = u & 0xffff0000u;
    float2 r; r.x = lo.f; r.y = hi.f; return r;
}

// tanh-approx GELU, exp2 domain; |err vs exact| <= ~4e-4, branchless.
__device__ __forceinline__ float fast_gelu(float z) {
    float z2 = z * z;
    float p  = z * fmaf(0.044715f, z2, 1.0f);
    float e  = __builtin_amdgcn_exp2f(-2.3022082f * p);
    float r  = __builtin_amdgcn_rcpf(1.0f + e);
    return z * r;
}

__device__ __forceinline__ float2 fma2(float a, float2 b, float2 c) {
    float2 r; r.x = fmaf(a, b.x, c.x); r.y = fmaf(a, b.y, c.y); return r;
}

__device__ __forceinline__ unsigned pack_bf16x2(float a, float b) {
    __hip_bfloat16 h0 = __float2bfloat16(a);
    __hip_bfloat16 h1 = __float2bfloat16(b);
    unsigned short u0, u1;
    __builtin_memcpy(&u0, &h0, 2);
    __builtin_memcpy(&u1, &h1, 2);
    return (unsigned)u0 | ((unsigned)u1 << 16);
}

// --- K1: fused x->bf16 convert (blocks 0..1249) + degree atomics (rest) ---
__global__ __launch_bounds__(256) void k_pre(
    const float* __restrict__ x, __hip_bfloat16* __restrict__ xb,
    const int* __restrict__ ei, int* __restrict__ dr, int* __restrict__ dc)
{
    int b = blockIdx.x;
    if (b < 1250) {
        int i = (b * 256 + threadIdx.x) * 4;
        float4 v = *(const float4*)(x + i);
        xb[i + 0] = __float2bfloat16(v.x);
        xb[i + 1] = __float2bfloat16(v.y);
        xb[i + 2] = __float2bfloat16(v.z);
        xb[i + 3] = __float2bfloat16(v.w);
    } else {
        int e = (b - 1250) * 256 + threadIdx.x;   // 2500 blocks cover N_EDGES
        atomicAdd(&dr[ei[e]], 1);
        atomicAdd(&dc[ei[N_EDGES + e]], 1);
    }
}

// --- K2: exclusive scan of dc -> off, plus inv-sqrt degrees ---
__global__ __launch_bounds__(1024) void k_scan(
    const int* __restrict__ dr, const int* __restrict__ dc,
    int* __restrict__ off, float* __restrict__ ir, float* __restrict__ ic)
{
    __shared__ int shp[1024];
    int t = threadIdx.x;
    int base = t * 10;
    int loc[10];
    int s = 0;
#pragma unroll
    for (int j = 0; j < 10; j++) {
        int i = base + j;
        int v = (i < N_NODES) ? dc[i] : 0;
        loc[j] = s;
        s += v;
    }
    shp[t] = s;
    __syncthreads();
    for (int st = 1; st < 1024; st <<= 1) {
        int a = (t >= st) ? shp[t - st] : 0;
        __syncthreads();
        shp[t] += a;
        __syncthreads();
    }
    int excl = shp[t] - s;
#pragma unroll
    for (int j = 0; j < 10; j++) {
        int i = base + j;
        if (i < N_NODES) {
            off[i] = excl + loc[j];
            ir[i] = rsqrtf((float)(dr[i] + 1));
            ic[i] = rsqrtf((float)(dc[i] + 1));
        }
    }
    if (t == 1023) off[N_NODES] = shp[1023];
}

// --- K3: scatter edge ids into destination buckets (proven since R5) ---
__global__ void k_scatter(const int* __restrict__ ei, const int* __restrict__ off,
                          int* __restrict__ cur, int* __restrict__ bucket) {
    int e = blockIdx.x * blockDim.x + threadIdx.x;
    if (e < N_EDGES) {
        int c = ei[N_EDGES + e];
        int pos = atomicAdd(&cur[c], 1);
        bucket[off[c] + pos] = e;
    }
}

// --- K4: slot-order message kernel. Sequential bucket read, random SMALL
//     gathers (ei/ew 4 B L2-resident, ea 64 B rows via 4-lane 16 B loads into
//     LDS), msg pre-scaled by ir[row]*ew, SEQUENTIAL NT row writes. ---
__global__ __launch_bounds__(256) void k_msg2(
    const int* __restrict__ bucket,
    const int* __restrict__ ei, const float* __restrict__ ew,
    const float* __restrict__ ea,
    const __hip_bfloat16* __restrict__ xb,
    const float* __restrict__ Wb, const float* __restrict__ bb,
    const float* __restrict__ ir,
    __hip_bfloat16* __restrict__ msg)
{
    int s0 = blockIdx.x * SPB;                 // grid = N_EDGES/SPB exactly
    int t = threadIdx.x;
    int p = t & 63;                            // channel pair
    int w = t >> 6;                            // wave 0..3

    __shared__ __align__(16) float sl_ea[SPB][BF];
    __shared__ int   sl_r[SPB];
    __shared__ float sl_s[SPB];
    __shared__ int   sl_e[SPB];

    if (t < SPB) {
        int e = bucket[s0 + t];                // coalesced 128 B
        sl_e[t] = e;
        int r = ei[e];                         // L2-resident gather
        sl_r[t] = r;
        sl_s[t] = ir[r] * ew[e];               // row-side scale only
    }
    __syncthreads();
    if (t < 128) {                             // stage 32 ea rows: 4 lanes/row
        int j = t >> 2, o = (t & 3) * 4;
        float4 v = *(const float4*)(ea + (size_t)sl_e[j] * BF + o);
        *(float4*)&sl_ea[j][o] = v;
    }

    int c0 = p * 2;
    float2 wbv[BF];
#pragma unroll
    for (int k = 0; k < BF; k++) wbv[k] = *(const float2*)(Wb + (size_t)k * C + c0);
    float2 bbv = *(const float2*)(bb + c0);
    __syncthreads();

#pragma unroll 4
    for (int jj = 0; jj < SPB / 4; jj++) {
        int j = w * (SPB / 4) + jj;            // wave w owns 8 consecutive slots
        const float4* er = (const float4*)sl_ea[j];   // wave-uniform broadcast
        float4 q0 = er[0], q1 = er[1], q2 = er[2], q3 = er[3];

        float2 emb = bbv;
        emb = fma2(q0.x, wbv[0],  emb); emb = fma2(q0.y, wbv[1],  emb);
        emb = fma2(q0.z, wbv[2],  emb); emb = fma2(q0.w, wbv[3],  emb);
        emb = fma2(q1.x, wbv[4],  emb); emb = fma2(q1.y, wbv[5],  emb);
        emb = fma2(q1.z, wbv[6],  emb); emb = fma2(q1.w, wbv[7],  emb);
        emb = fma2(q2.x, wbv[8],  emb); emb = fma2(q2.y, wbv[9],  emb);
        emb = fma2(q2.z, wbv[10], emb); emb = fma2(q2.w, wbv[11], emb);
        emb = fma2(q3.x, wbv[12], emb); emb = fma2(q3.y, wbv[13], emb);
        emb = fma2(q3.z, wbv[14], emb); emb = fma2(q3.w, wbv[15], emb);

        int r = sl_r[j];
        float s = sl_s[j];
        float2 xf = bf2_to_f2(*((const unsigned*)(xb + (size_t)r * C) + p));
        float m0 = fast_gelu(xf.x + emb.x) * s;
        float m1 = fast_gelu(xf.y + emb.y) * s;
        __builtin_nontemporal_store(pack_bf16x2(m0, m1),
            (unsigned*)(msg + (size_t)(s0 + j) * C) + p);  // sequential rows
    }
}

// --- K5: contiguous segmented sum (x ic[n]) + self-loop + GEMV epilogue ---
__global__ __launch_bounds__(256) void k_sum2(
    const __hip_bfloat16* __restrict__ msg,
    const __hip_bfloat16* __restrict__ xb,
    const float* __restrict__ ir, const float* __restrict__ ic,
    const int* __restrict__ off,
    const float* __restrict__ Wl, const float* __restrict__ bl,
    float* __restrict__ out)
{
    int n = blockIdx.x;
    int t = threadIdx.x;
    int w = t >> 6;
    int lane = t & 63;
    int c0 = lane * 2;

    int i0 = off[n], i1 = off[n + 1];
    const unsigned* mb = (const unsigned*)msg;

    float2 a0 = make_float2(0.f, 0.f), a1 = make_float2(0.f, 0.f);
    int i = i0 + w;
    for (; i + 4 < i1; i += 8) {
        unsigned u0 = __builtin_nontemporal_load(mb + (size_t)i * 64 + lane);
        unsigned u1 = __builtin_nontemporal_load(mb + (size_t)(i + 4) * 64 + lane);
        float2 f0 = bf2_to_f2(u0);
        float2 f1 = bf2_to_f2(u1);
        a0.x += f0.x; a0.y += f0.y;
        a1.x += f1.x; a1.y += f1.y;
    }
    if (i < i1) {
        float2 f0 = bf2_to_f2(__builtin_nontemporal_load(mb + (size_t)i * 64 + lane));
        a0.x += f0.x; a0.y += f0.y;
    }
    a0.x += a1.x; a0.y += a1.y;

    __shared__ float shp[4][C];
    __shared__ float shs[C];
    __shared__ float sho[2][C];
    shp[w][c0] = a0.x; shp[w][c0 + 1] = a0.y;
    __syncthreads();
    if (t < C) {
        float v = shp[0][t] + shp[1][t] + shp[2][t] + shp[3][t];
        float xv = __bfloat162float(xb[(size_t)n * C + t]);
        shs[t] = (v + fast_gelu(xv) * ir[n]) * ic[n];   // col factor folded here
    }
    __syncthreads();

    int ch = t & 127, half = t >> 7;
    float o = 0.f;
    const float4* shv = (const float4*)shs + half * 16;
    const float* wcol = Wl + (size_t)(half * 64) * C + ch;
#pragma unroll 8
    for (int k4 = 0; k4 < 16; k4++) {
        float4 sv = shv[k4];
        o = fmaf(sv.x, wcol[(size_t)(k4 * 4 + 0) * C], o);
        o = fmaf(sv.y, wcol[(size_t)(k4 * 4 + 1) * C], o);
        o = fmaf(sv.z, wcol[(size_t)(k4 * 4 + 2) * C], o);
        o = fmaf(sv.w, wcol[(size_t)(k4 * 4 + 3) * C], o);
    }
    sho[half][ch] = o;
    __syncthreads();
    if (t < C) out[(size_t)n * C + t] = bl[t] + sho[0][t] + sho[1][t];
}

// ---------------- fallback path (round-5 structure, ws-lean, proven) --------
template <bool USEBF>
__global__ __launch_bounds__(512) void k_node_fb(
    const float* __restrict__ x, const __hip_bfloat16* __restrict__ xb,
    const float* __restrict__ ea, const float* __restrict__ ew,
    const float* __restrict__ Wb, const float* __restrict__ bb,
    const int* __restrict__ ei,
    const float* __restrict__ ir, const float* __restrict__ ic,
    const int* __restrict__ off, const int* __restrict__ bucket,
    const float* __restrict__ Wl, const float* __restrict__ bl,
    float* __restrict__ out)
{
    int n = blockIdx.x;
    int t = threadIdx.x & (C - 1);
    int g = threadIdx.x >> 7;
    float icn = ic[n];
    float wb[BF];
#pragma unroll
    for (int k = 0; k < BF; k++) wb[k] = Wb[(size_t)k * C + t];
    float bbt = bb[t];
    float acc = 0.0f;
    if (g == 0) {
        float xv = USEBF ? __bfloat162float(xb[(size_t)n * C + t]) : x[(size_t)n * C + t];
        acc = fast_gelu(xv) * (ir[n] * icn);
    }
    int o0 = off[n], o1 = off[n + 1];
    for (int i = o0 + g; i < o1; i += 4) {
        int e = __builtin_amdgcn_readfirstlane(bucket[i]);
        int r = ei[e];
        float s = ir[r] * icn * ew[e];
        const float4* eapt = (const float4*)(ea + (size_t)e * BF);
        float4 q0 = eapt[0], q1 = eapt[1], q2 = eapt[2], q3 = eapt[3];
        float emb = bbt;
        emb = fmaf(q0.x, wb[0], emb);  emb = fmaf(q0.y, wb[1], emb);
        emb = fmaf(q0.z, wb[2], emb);  emb = fmaf(q0.w, wb[3], emb);
        emb = fmaf(q1.x, wb[4], emb);  emb = fmaf(q1.y, wb[5], emb);
        emb = fmaf(q1.z, wb[6], emb);  emb = fmaf(q1.w, wb[7], emb);
        emb = fmaf(q2.x, wb[8], emb);  emb = fmaf(q2.y, wb[9], emb);
        emb = fmaf(q2.z, wb[10], emb); emb = fmaf(q2.w, wb[11], emb);
        emb = fmaf(q3.x, wb[12], emb); emb = fmaf(q3.y, wb[13], emb);
        emb = fmaf(q3.z, wb[14], emb); emb = fmaf(q3.w, wb[15], emb);
        float xv = USEBF ? __bfloat162float(xb[(size_t)r * C + t]) : x[(size_t)r * C + t];
        acc = fmaf(fast_gelu(xv + emb), s, acc);
    }
    __shared__ float shp[4][C];
    __shared__ float shs[C];
    shp[g][t] = acc;
    __syncthreads();
    if (threadIdx.x < C) {
        int k = threadIdx.x;
        shs[k] = shp[0][k] + shp[1][k] + shp[2][k] + shp[3][k];
    }
    __syncthreads();
    float o = 0.0f;
    int k0 = g * 32;
#pragma unroll 8
    for (int j = 0; j < 32; j++) {
        int k = k0 + j;
        o = fmaf(shs[k], Wl[(size_t)k * C + t], o);
    }
    shp[g][t] = o;
    __syncthreads();
    if (threadIdx.x < C) {
        int c = threadIdx.x;
        out[(size_t)n * C + c] = bl[c] + shp[0][c] + shp[1][c] + shp[2][c] + shp[3][c];
    }
}

__global__ __launch_bounds__(256) void k_cvt_fb(const float* __restrict__ x,
                                                __hip_bfloat16* __restrict__ xb) {
    int i = (blockIdx.x * 256 + threadIdx.x) * 4;
    float4 v = *(const float4*)(x + i);
    xb[i + 0] = __float2bfloat16(v.x);
    xb[i + 1] = __float2bfloat16(v.y);
    xb[i + 2] = __float2bfloat16(v.z);
    xb[i + 3] = __float2bfloat16(v.w);
}

__global__ void k_deg_fb(const int* __restrict__ ei, int* __restrict__ dr, int* __restrict__ dc) {
    int e = blockIdx.x * blockDim.x + threadIdx.x;
    if (e < N_EDGES) {
        atomicAdd(&dr[ei[e]], 1);
        atomicAdd(&dc[ei[N_EDGES + e]], 1);
    }
}

extern "C" void kernel_launch(void* const* d_in, const int* in_sizes, int n_in,
                              void* d_out, int out_size, void* d_ws, size_t ws_size,
                              hipStream_t stream) {
    const float* x  = (const float*)d_in[0];
    const float* ea = (const float*)d_in[1];
    const float* ew = (const float*)d_in[2];
    const float* Wb = (const float*)d_in[3];
    const float* bb = (const float*)d_in[4];
    const float* Wl = (const float*)d_in[5];
    const float* bl = (const float*)d_in[6];
    const int*   ei = (const int*)d_in[7];
    float* out = (float*)d_out;

    // full layout (u32 units): msg 40,960,000 | xb 640,000 | bucket 640,000 |
    //   off 10,304 | dr/dc/cur 3x10,240 | ir/ic 2x10,240
    const size_t need_full = (size_t)(40960000 + 2 * 640000 + 10304 + 5 * 10240) * 4;
    const size_t need_bf   = (size_t)(640000 + 640000 + 10304 + 5 * 10240) * 4;

    unsigned* w32 = (unsigned*)d_ws;
    if (ws_size >= need_full) {
        __hip_bfloat16* msg = (__hip_bfloat16*)w32;
        __hip_bfloat16* xb  = (__hip_bfloat16*)(w32 + 40960000);
        int*   bucket = (int*)(w32 + 40960000 + 640000);
        int*   off    = bucket + 640000;
        int*   dr     = off + 10304;
        int*   dc     = dr + 10240;
        int*   cur    = dc + 10240;
        float* ir     = (float*)(cur + 10240);
        float* ic     = ir + 10240;

        hipMemsetAsync(dr, 0, 3 * 10240 * sizeof(int), stream);   // dr, dc, cur
        k_pre<<<3750, 256, 0, stream>>>(x, xb, ei, dr, dc);
        k_scan<<<1, 1024, 0, stream>>>(dr, dc, off, ir, ic);
        k_scatter<<<(N_EDGES + 255) / 256, 256, 0, stream>>>(ei, off, cur, bucket);
        k_msg2<<<N_EDGES / SPB, 256, 0, stream>>>(bucket, ei, ew, ea, xb, Wb, bb, ir, msg);
        k_sum2<<<N_NODES, 256, 0, stream>>>(msg, xb, ir, ic, off, Wl, bl, out);
    } else {
        bool usebf = ws_size >= need_bf;
        __hip_bfloat16* xb = (__hip_bfloat16*)w32;
        int* bucket = (int*)(w32 + (usebf ? 640000 : 0));
        int* off    = bucket + 640000;
        int* dr     = off + 10304;
        int* dc     = dr + 10240;
        int* cur    = dc + 10240;
        float* ir   = (float*)(cur + 10240);
        float* ic   = ir + 10240;

        hipMemsetAsync(dr, 0, 3 * 10240 * sizeof(int), stream);
        if (usebf) k_cvt_fb<<<1250, 256, 0, stream>>>(x, xb);
        k_deg_fb<<<(N_EDGES + 255) / 256, 256, 0, stream>>>(ei, dr, dc);
        k_scan<<<1, 1024, 0, stream>>>(dr, dc, off, ir, ic);
        k_scatter<<<(N_EDGES + 255) / 256, 256, 0, stream>>>(ei, off, cur, bucket);
        if (usebf)
            k_node_fb<true><<<N_NODES, 512, 0, stream>>>(x, xb, ea, ew, Wb, bb, ei, ir, ic, off, bucket, Wl, bl, out);
        else
            k_node_fb<false><<<N_NODES, 512, 0, stream>>>(x, xb, ea, ew, Wb, bb, ei, ir, ic, off, bucket, Wl, bl, out);
    }
}